// Round 12
// baseline (130.917 us; speedup 1.0000x reference)
//
#include <hip/hip_runtime.h>

#define D 512
#define KT 32           // k-columns per tile; e[16][4] = 64 VGPRs
#define NT 16           // D / KT
#define LOG2E 1.44269504088896340736f

#if defined(__has_builtin)
#if __has_builtin(__builtin_amdgcn_exp2f)
#define EXP2(x) __builtin_amdgcn_exp2f(x)
#else
#define EXP2(x) exp2f(x)
#endif
#else
#define EXP2(x) exp2f(x)
#endif

// One block per batch row; E in registers. vs round-11:
//  - KT 64->32: e[16][8]->e[16][4] halves the persistent register tile so the
//    kernel fits 128 VGPR -> __launch_bounds__(256,4) -> 4 waves/SIMD,
//    4 blocks/CU (round-11 sat at ~2 waves/SIMD with e in AGPRs, 37% idle
//    issue slots behind barriers).
//  - wave-local z pre-reduce (3x shfl_xor over jp within each wave): finalize
//    reads 4 floats instead of 32; zred LDS 8.7KB -> 512B.
// Thread (jp = tid>>3, k8 = tid&7) owns rows j = jj*32+jp (16) and
// k = k0 + k8*4 + c (4) per tile.
__global__ __launch_bounds__(256, 4) void attn_kernel(
    const float* __restrict__ a, const float* __restrict__ b,
    float* __restrict__ attn) {
  __shared__ float a_s[D];       // 2 KB
  __shared__ float zredw[128];   // 512 B: [wave][32 k]
  __shared__ float c_s[KT];      // 128 B
  __shared__ float attn_s[D];    // 2 KB

  const int bt = blockIdx.x;
  const int tid = threadIdx.x;
  const float* __restrict__ ap = a + (size_t)bt * D;
  const float* __restrict__ bp = b + (size_t)bt * D;

  {  // stage a row
    float2 va = *(const float2*)(ap + tid * 2);
    a_s[tid * 2] = va.x;
    a_s[tid * 2 + 1] = va.y;
  }

  const int k8 = tid & 7;   // owns 4 k's per tile
  const int jp = tid >> 3;  // 0..31, rows j === jp (mod 32)
  const int wv = tid >> 6;  // wave id 0..3

  float breg[16];
#pragma unroll
  for (int jj = 0; jj < 16; ++jj) breg[jj] = bp[jj * 32 + jp];

  float part[16];
#pragma unroll
  for (int jj = 0; jj < 16; ++jj) part[jj] = 0.f;

  __syncthreads();

  for (int t = 0; t < NT; ++t) {
    const int k0 = t * KT;
    float alk[4];
#pragma unroll
    for (int c = 0; c < 4; ++c) alk[c] = a_s[k0 + k8 * 4 + c] * LOG2E;

    float e[16][4];
    float z[4] = {0.f, 0.f, 0.f, 0.f};

    // ---- pass 1: 64 exps into registers, z partials in f32
#pragma unroll
    for (int jj = 0; jj < 16; ++jj) {
      const float bj = breg[jj];
#pragma unroll
      for (int c = 0; c < 4; ++c) {
        const float ev = EXP2(alk[c] * bj);
        e[jj][c] = ev;
        z[c] += ev;
      }
    }

    // ---- wave-local reduce over jp_local (lanes xor 8/16/32 share k8)
#pragma unroll
    for (int c = 0; c < 4; ++c) {
      float v = z[c];
      v += __shfl_xor(v, 8);
      v += __shfl_xor(v, 16);
      v += __shfl_xor(v, 32);
      z[c] = v;
    }
    if ((tid & 63) < 8) {  // lane k8 of each wave: 8 lanes x b128, banks 0..31
      *(float4*)&zredw[wv * 32 + k8 * 4] = make_float4(z[0], z[1], z[2], z[3]);
    }
    __syncthreads();
    if (tid < KT) {  // finalize: 4 reads + div
      const float Z =
          zredw[tid] + zredw[32 + tid] + zredw[64 + tid] + zredw[96 + tid];
      c_s[tid] = a_s[k0 + tid] / Z;
    }
    __syncthreads();

    // ---- pass 2: register fma
    float cs[4];
    *(float4*)&cs[0] = *(const float4*)&c_s[k8 * 4];
#pragma unroll
    for (int jj = 0; jj < 16; ++jj) {
#pragma unroll
      for (int c = 0; c < 4; ++c) part[jj] = fmaf(cs[c], e[jj][c], part[jj]);
    }
    // next tile's zredw writes happen after this point (post barrier 2), so
    // they cannot race this tile's finalize reads.
  }

  // reduce over the 8 k8-lanes (consecutive lanes, xor 1/2/4)
#pragma unroll
  for (int jj = 0; jj < 16; ++jj) {
    float v = part[jj];
    v += __shfl_xor(v, 1);
    v += __shfl_xor(v, 2);
    v += __shfl_xor(v, 4);
    part[jj] = v;
  }
  if (k8 == 0) {
#pragma unroll
    for (int jj = 0; jj < 16; ++jj) attn_s[jj * 32 + jp] = part[jj];
  }
  __syncthreads();
  {  // coalesced float2 store
    float2 v = *(const float2*)&attn_s[tid * 2];
    *(float2*)(attn + (size_t)bt * D + tid * 2) = v;
  }
}

// out = a + attn @ W^T + bias. UNCHANGED from round 11 (passed; never in the
// top-5 dispatch list -> not the measured bottleneck; keep attribution clean).
__global__ __launch_bounds__(256) void gemm_kernel(
    const float* __restrict__ attn, const float* __restrict__ W,
    const float* __restrict__ a, const float* __restrict__ bias,
    float* __restrict__ out) {
  __shared__ float As[64][36];  // [k][m], +4 pad
  __shared__ float Bs[64][36];  // [k][n]
  const int tid = threadIdx.x;
  const int bx = blockIdx.x;  // 0..15  N tiles
  const int by = blockIdx.y;  // 0..31  M tiles
  const int tx = tid & 15;
  const int ty = tid >> 4;
  const int r = tid >> 3;        // 0..31 staging row
  const int c0 = (tid & 7) * 8;  // 0..56 staging k-offset
  float acc[2][2] = {};

  for (int k0 = 0; k0 < D; k0 += 64) {
    const float4 va0 = *(const float4*)(attn + (size_t)(by * 32 + r) * D + k0 + c0);
    const float4 va1 = *(const float4*)(attn + (size_t)(by * 32 + r) * D + k0 + c0 + 4);
    const float4 vw0 = *(const float4*)(W + (size_t)(bx * 32 + r) * D + k0 + c0);
    const float4 vw1 = *(const float4*)(W + (size_t)(bx * 32 + r) * D + k0 + c0 + 4);
    As[c0 + 0][r] = va0.x; As[c0 + 1][r] = va0.y;
    As[c0 + 2][r] = va0.z; As[c0 + 3][r] = va0.w;
    As[c0 + 4][r] = va1.x; As[c0 + 5][r] = va1.y;
    As[c0 + 6][r] = va1.z; As[c0 + 7][r] = va1.w;
    Bs[c0 + 0][r] = vw0.x; Bs[c0 + 1][r] = vw0.y;
    Bs[c0 + 2][r] = vw0.z; Bs[c0 + 3][r] = vw0.w;
    Bs[c0 + 4][r] = vw1.x; Bs[c0 + 5][r] = vw1.y;
    Bs[c0 + 6][r] = vw1.z; Bs[c0 + 7][r] = vw1.w;
    __syncthreads();
#pragma unroll 16
    for (int kk = 0; kk < 64; ++kk) {
      const float2 af = *(const float2*)&As[kk][ty * 2];
      const float2 bf = *(const float2*)&Bs[kk][tx * 2];
      acc[0][0] = fmaf(af.x, bf.x, acc[0][0]);
      acc[0][1] = fmaf(af.x, bf.y, acc[0][1]);
      acc[1][0] = fmaf(af.y, bf.x, acc[1][0]);
      acc[1][1] = fmaf(af.y, bf.y, acc[1][1]);
    }
    __syncthreads();
  }

  const int m0 = by * 32 + ty * 2;
  const int n0 = bx * 32 + tx * 2;
  const float2 bv = *(const float2*)&bias[n0];
#pragma unroll
  for (int i = 0; i < 2; ++i) {
    const float2 av = *(const float2*)&a[(size_t)(m0 + i) * D + n0];
    float2 o;
    o.x = av.x + acc[i][0] + bv.x;
    o.y = av.y + acc[i][1] + bv.y;
    *(float2*)(out + (size_t)(m0 + i) * D + n0) = o;
  }
}

extern "C" void kernel_launch(void* const* d_in, const int* in_sizes, int n_in,
                              void* d_out, int out_size, void* d_ws,
                              size_t ws_size, hipStream_t stream) {
  const float* a = (const float*)d_in[0];
  const float* b = (const float*)d_in[1];
  const float* W = (const float*)d_in[2];
  const float* bias = (const float*)d_in[3];
  float* out = (float*)d_out;
  float* attn = (float*)d_ws;  // 2 MB scratch

  attn_kernel<<<1024, 256, 0, stream>>>(a, b, attn);
  gemm_kernel<<<dim3(16, 32), 256, 0, stream>>>(attn, W, a, bias, out);
}